// Round 1
// 10347.372 us; speedup vs baseline: 2.6782x; 2.6782x over previous
//
#include <hip/hip_runtime.h>
#include <math.h>

#define N_ROWS 8192
#define DIM 768
#define M_CB 64
#define K_CB 256
#define SUBDIM 12
#define H1 8192
#define H2 16384
#define LN_EPS 1e-5f

typedef _Float16 h8 __attribute__((ext_vector_type(8)));
typedef _Float16 h4 __attribute__((ext_vector_type(4)));
typedef float f32x4 __attribute__((ext_vector_type(4)));

// global -> LDS direct copy, 16B per lane.  LDS dest must be linear
// (wave-uniform base + lane*16); all swizzling is done on the GLOBAL side.
#define GLD16(gp, lp)                                                         \
  __builtin_amdgcn_global_load_lds(                                           \
      (const __attribute__((address_space(1))) void*)(gp),                    \
      (__attribute__((address_space(3))) void*)(lp), 16, 0, 0)

// ---------------------------------------------------------------------------
// Kernel 1: LayerNorm.  One block (256 threads) per row of x (768 cols).
// ---------------------------------------------------------------------------
__global__ __launch_bounds__(256) void k_layernorm(
    const float* __restrict__ x, const float* __restrict__ gamma,
    const float* __restrict__ beta, float* __restrict__ xn) {
  __shared__ float sbuf[8];
  int n = blockIdx.x;
  int t = threadIdx.x;
  const float* row = x + (size_t)n * DIM;
  float v0 = row[t], v1 = row[t + 256], v2 = row[t + 512];
  float s = v0 + v1 + v2;
#pragma unroll
  for (int o = 32; o > 0; o >>= 1) s += __shfl_down(s, o);
  if ((t & 63) == 0) sbuf[t >> 6] = s;
  __syncthreads();
  float mean = (sbuf[0] + sbuf[1] + sbuf[2] + sbuf[3]) * (1.0f / 768.0f);
  float d0 = v0 - mean, d1 = v1 - mean, d2 = v2 - mean;
  float q = d0 * d0 + d1 * d1 + d2 * d2;
#pragma unroll
  for (int o = 32; o > 0; o >>= 1) q += __shfl_down(q, o);
  if ((t & 63) == 0) sbuf[4 + (t >> 6)] = q;
  __syncthreads();
  float var = (sbuf[4] + sbuf[5] + sbuf[6] + sbuf[7]) * (1.0f / 768.0f);
  float rstd = 1.0f / sqrtf(var + LN_EPS);
  float* orow = xn + (size_t)n * DIM;
  orow[t]       = d0 * rstd * gamma[t]       + beta[t];
  orow[t + 256] = d1 * rstd * gamma[t + 256] + beta[t + 256];
  orow[t + 512] = d2 * rstd * gamma[t + 512] + beta[t + 512];
}

// ---------------------------------------------------------------------------
// Kernel 2: PQ argmin over K=256 codewords per (n, m).  One wave per (n, m).
// Unchanged: must remain bit-identical (spike location must match exactly).
// ---------------------------------------------------------------------------
__global__ __launch_bounds__(256) void k_pq_argmin(
    const float* __restrict__ x, const float* __restrict__ cb,
    int* __restrict__ kmin) {
#pragma clang fp contract(off)
  int n = blockIdx.x;
  int wave = threadIdx.x >> 6;
  int lane = threadIdx.x & 63;
  int m = blockIdx.y * 4 + wave;
  const float* xr = x + (size_t)n * DIM + m * SUBDIM;
  float xv[SUBDIM];
#pragma unroll
  for (int d = 0; d < SUBDIM; d++) xv[d] = xr[d];
  float p[SUBDIM];
#pragma unroll
  for (int d = 0; d < SUBDIM; d++) p[d] = xv[d] * xv[d];
  float xsq = ((p[0] + p[1]) + (p[2] + p[3])) + ((p[4] + p[5]) + (p[6] + p[7]));
  xsq = xsq + p[8]; xsq = xsq + p[9]; xsq = xsq + p[10]; xsq = xsq + p[11];

  float bestv = INFINITY;
  int besti = 0;
#pragma unroll
  for (int j = 0; j < 4; j++) {
    int k = lane + 64 * j;
    const float* cv = cb + ((size_t)m * K_CB + k) * SUBDIM;
    float c[SUBDIM];
#pragma unroll
    for (int d = 0; d < SUBDIM; d++) c[d] = cv[d];
    float q[SUBDIM];
#pragma unroll
    for (int d = 0; d < SUBDIM; d++) q[d] = c[d] * c[d];
    float csq = ((q[0] + q[1]) + (q[2] + q[3])) + ((q[4] + q[5]) + (q[6] + q[7]));
    csq = csq + q[8]; csq = csq + q[9]; csq = csq + q[10]; csq = csq + q[11];
    float cr = 0.0f;
#pragma unroll
    for (int d = 0; d < SUBDIM; d++) cr = cr + xv[d] * c[d];
    float dist = (xsq + csq) - 2.0f * cr;
    if (dist < bestv) { bestv = dist; besti = k; }
  }
#pragma unroll
  for (int o = 32; o > 0; o >>= 1) {
    float ov = __shfl_down(bestv, o);
    int oi = __shfl_down(besti, o);
    if (ov < bestv || (ov == bestv && oi < besti)) { bestv = ov; besti = oi; }
  }
  if (lane == 0) kmin[(size_t)n * M_CB + m] = besti;
}

// ---------------------------------------------------------------------------
// Kernel 3 (new path): h = tanh(xn @ W1 + b1), epilogue emits the split-fp16
// planes  h_hi = fp16(256*h),  h_lo = fp16(256*h - h_hi).
// ---------------------------------------------------------------------------
__global__ __launch_bounds__(256) void k_gemm1_tanh_split(
    const float* __restrict__ A, const float* __restrict__ B,
    const float* __restrict__ bias, _Float16* __restrict__ Chi,
    _Float16* __restrict__ Clo) {
  __shared__ float As[16][132];
  __shared__ float Bs[16][132];
  int tid = threadIdx.x;
  int rowBase = blockIdx.x * 128;
  int colBase = blockIdx.y * 128;
  int tx = tid & 15, ty = tid >> 4;
  int ar = tid >> 2;
  int ac = (tid & 3) * 4;
  int br = tid >> 5;
  int bc = (tid & 31) * 4;
  float acc[8][8] = {};
  const float* Aptr0 = A + (size_t)(rowBase + ar) * DIM + ac;
  const float* Aptr1 = A + (size_t)(rowBase + ar + 64) * DIM + ac;
  const float* Bptr0 = B + (size_t)br * H1 + colBase + bc;
  const float* Bptr1 = B + (size_t)(br + 8) * H1 + colBase + bc;
  for (int k0 = 0; k0 < DIM; k0 += 16) {
    float4 a0 = *(const float4*)(Aptr0 + k0);
    float4 a1 = *(const float4*)(Aptr1 + k0);
    float4 b0 = *(const float4*)(Bptr0 + (size_t)k0 * H1);
    float4 b1 = *(const float4*)(Bptr1 + (size_t)k0 * H1);
    __syncthreads();
    As[ac + 0][ar] = a0.x; As[ac + 1][ar] = a0.y;
    As[ac + 2][ar] = a0.z; As[ac + 3][ar] = a0.w;
    As[ac + 0][ar + 64] = a1.x; As[ac + 1][ar + 64] = a1.y;
    As[ac + 2][ar + 64] = a1.z; As[ac + 3][ar + 64] = a1.w;
    *(float4*)&Bs[br][bc] = b0;
    *(float4*)&Bs[br + 8][bc] = b1;
    __syncthreads();
#pragma unroll
    for (int kk = 0; kk < 16; kk++) {
      float av[8], bv[8];
      *(float4*)&av[0] = *(const float4*)&As[kk][ty * 8];
      *(float4*)&av[4] = *(const float4*)&As[kk][ty * 8 + 4];
      *(float4*)&bv[0] = *(const float4*)&Bs[kk][tx * 8];
      *(float4*)&bv[4] = *(const float4*)&Bs[kk][tx * 8 + 4];
#pragma unroll
      for (int i = 0; i < 8; i++)
#pragma unroll
        for (int j = 0; j < 8; j++)
          acc[i][j] = fmaf(av[i], bv[j], acc[i][j]);
    }
  }
  float bcol[8];
#pragma unroll
  for (int j = 0; j < 8; j++) bcol[j] = bias[colBase + tx * 8 + j];
#pragma unroll
  for (int i = 0; i < 8; i++) {
    int r = rowBase + ty * 8 + i;
    h8 hv, lv;
#pragma unroll
    for (int j = 0; j < 8; j++) {
      float t = tanhf(acc[i][j] + bcol[j]) * 256.0f;  // *256 is exact
      _Float16 hi = (_Float16)t;
      hv[j] = hi;
      lv[j] = (_Float16)(t - (float)hi);
    }
    size_t off = (size_t)r * H1 + colBase + tx * 8;
    *(h8*)(Chi + off) = hv;
    *(h8*)(Clo + off) = lv;
  }
}

// ---------------------------------------------------------------------------
// Kernel 3b (fallback path): original fp32-h variant.
// ---------------------------------------------------------------------------
__global__ __launch_bounds__(256) void k_gemm1_tanh_f32(
    const float* __restrict__ A, const float* __restrict__ B,
    const float* __restrict__ bias, float* __restrict__ C) {
  __shared__ float As[16][132];
  __shared__ float Bs[16][132];
  int tid = threadIdx.x;
  int rowBase = blockIdx.x * 128;
  int colBase = blockIdx.y * 128;
  int tx = tid & 15, ty = tid >> 4;
  int ar = tid >> 2;
  int ac = (tid & 3) * 4;
  int br = tid >> 5;
  int bc = (tid & 31) * 4;
  float acc[8][8] = {};
  const float* Aptr0 = A + (size_t)(rowBase + ar) * DIM + ac;
  const float* Aptr1 = A + (size_t)(rowBase + ar + 64) * DIM + ac;
  const float* Bptr0 = B + (size_t)br * H1 + colBase + bc;
  const float* Bptr1 = B + (size_t)(br + 8) * H1 + colBase + bc;
  for (int k0 = 0; k0 < DIM; k0 += 16) {
    float4 a0 = *(const float4*)(Aptr0 + k0);
    float4 a1 = *(const float4*)(Aptr1 + k0);
    float4 b0 = *(const float4*)(Bptr0 + (size_t)k0 * H1);
    float4 b1 = *(const float4*)(Bptr1 + (size_t)k0 * H1);
    __syncthreads();
    As[ac + 0][ar] = a0.x; As[ac + 1][ar] = a0.y;
    As[ac + 2][ar] = a0.z; As[ac + 3][ar] = a0.w;
    As[ac + 0][ar + 64] = a1.x; As[ac + 1][ar + 64] = a1.y;
    As[ac + 2][ar + 64] = a1.z; As[ac + 3][ar + 64] = a1.w;
    *(float4*)&Bs[br][bc] = b0;
    *(float4*)&Bs[br + 8][bc] = b1;
    __syncthreads();
#pragma unroll
    for (int kk = 0; kk < 16; kk++) {
      float av[8], bv[8];
      *(float4*)&av[0] = *(const float4*)&As[kk][ty * 8];
      *(float4*)&av[4] = *(const float4*)&As[kk][ty * 8 + 4];
      *(float4*)&bv[0] = *(const float4*)&Bs[kk][tx * 8];
      *(float4*)&bv[4] = *(const float4*)&Bs[kk][tx * 8 + 4];
#pragma unroll
      for (int i = 0; i < 8; i++)
#pragma unroll
        for (int j = 0; j < 8; j++)
          acc[i][j] = fmaf(av[i], bv[j], acc[i][j]);
    }
  }
  float bcol[8];
#pragma unroll
  for (int j = 0; j < 8; j++) bcol[j] = bias[colBase + tx * 8 + j];
#pragma unroll
  for (int i = 0; i < 8; i++) {
    int r = rowBase + ty * 8 + i;
    float4 o0, o1;
    o0.x = tanhf(acc[i][0] + bcol[0]); o0.y = tanhf(acc[i][1] + bcol[1]);
    o0.z = tanhf(acc[i][2] + bcol[2]); o0.w = tanhf(acc[i][3] + bcol[3]);
    o1.x = tanhf(acc[i][4] + bcol[4]); o1.y = tanhf(acc[i][5] + bcol[5]);
    o1.z = tanhf(acc[i][6] + bcol[6]); o1.w = tanhf(acc[i][7] + bcol[7]);
    float* crow = C + (size_t)r * H1 + colBase + tx * 8;
    *(float4*)(crow) = o0;
    *(float4*)(crow + 4) = o1;
  }
}

// ---------------------------------------------------------------------------
// Kernel 4 (new path): transpose+split W2.
// W2[k][c] fp32  ->  Whi/Wlo[c][k] fp16 with Whi=fp16(256*w), Wlo=residual.
// The *256 scale keeps the lo plane out of fp16-denormal range.
// ---------------------------------------------------------------------------
__global__ __launch_bounds__(256) void k_w2split(
    const float* __restrict__ W2, _Float16* __restrict__ Whi,
    _Float16* __restrict__ Wlo) {
  __shared__ float tile[64][65];
  int tid = threadIdx.x;
  int kb = blockIdx.x * 64;
  int cb = blockIdx.y * 64;
#pragma unroll
  for (int it = 0; it < 4; it++) {
    int idx = it * 256 + tid;
    int cc = (idx & 15) * 4;
    int kk = idx >> 4;
    float4 v = *(const float4*)(W2 + (size_t)(kb + kk) * H2 + cb + cc);
    tile[kk][cc] = v.x; tile[kk][cc + 1] = v.y;
    tile[kk][cc + 2] = v.z; tile[kk][cc + 3] = v.w;
  }
  __syncthreads();
#pragma unroll
  for (int it = 0; it < 4; it++) {
    int idx = it * 256 + tid;
    int kk4 = (idx & 15) * 4;
    int cc = idx >> 4;
    h4 hv, lv;
#pragma unroll
    for (int j = 0; j < 4; j++) {
      float wv = tile[kk4 + j][cc] * 256.0f;  // exact
      _Float16 hi = (_Float16)wv;
      hv[j] = hi;
      lv[j] = (_Float16)(wv - (float)hi);
    }
    size_t off = (size_t)(cb + cc) * H1 + kb + kk4;
    *(h4*)(Whi + off) = hv;
    *(h4*)(Wlo + off) = lv;
  }
}

// ---------------------------------------------------------------------------
// Kernel 5 (new path): GEMM2 on the matrix pipe.  Split-fp16, 3 MFMA products
// per fragment pair: acc += ah*bh + ah*bl + al*bh; logits = acc/65536.
// Tile 64 rows x 256 cols (one m-group), BK=32, 512 threads = 8 waves,
// per-wave 64x32 output = acc[4][2] of 16x16x32 fragments.
// Staging via global_load_lds (linear LDS dest); the k-chunk slot is
// XOR-swizzled (slot ^= (row>>1)&3) on the GLOBAL source and undone at the
// ds_read_b128 fragment read -> 8-way bank conflict becomes free 2-way.
// Fused epilogue: relu/interp/spike/gumbel/argmax/one-hot.
// ---------------------------------------------------------------------------
__global__ __launch_bounds__(512, 4) void k_gemm2_mfma(
    const _Float16* __restrict__ Ahi, const _Float16* __restrict__ Alo,
    const _Float16* __restrict__ Bhi, const _Float16* __restrict__ Blo,
    const float* __restrict__ bias, const int* __restrict__ kmin,
    const float* __restrict__ interp_p, const float* __restrict__ gumbel,
    float* __restrict__ out) {
#pragma clang fp contract(off)
  __shared__ _Float16 As_hi[64 * 32];
  __shared__ _Float16 As_lo[64 * 32];
  __shared__ _Float16 Bs_hi[256 * 32];
  __shared__ _Float16 Bs_lo[256 * 32];
  __shared__ float redV[64][8];
  __shared__ int   redI[64][8];
  __shared__ int   bestk[64];

  const int tid = threadIdx.x;
  const int rowBase = blockIdx.x * 64;
  const int mcb = blockIdx.y;
  const int w = tid >> 6;        // wave 0..7 -> cols [w*32, w*32+32)
  const int lane = tid & 63;
  const int li = lane & 15, g = lane >> 4;

  // ---- staging pointers (A: one chunk/thread, B: 2+2 chunks/thread) ----
  const int achunk = tid & 255;                 // 64 rows * 4 k-chunks
  const int arow = achunk >> 2;
  const int akc = (achunk & 3) ^ ((arow >> 1) & 3);   // pre-swizzled source
  const _Float16* srcA = (tid < 256 ? Ahi : Alo) +
      ((size_t)(rowBase + arow) * H1 + akc * 8);
  _Float16* dstA = (tid < 256 ? As_hi : As_lo) + achunk * 8;  // linear dest

  const _Float16* srcBh[2];
  const _Float16* srcBl[2];
  _Float16* dstBh[2];
  _Float16* dstBl[2];
#pragma unroll
  for (int it = 0; it < 2; it++) {
    int ch = it * 512 + tid;                    // 256 cols * 4 k-chunks
    int bcol = ch >> 2;
    int bkc = (ch & 3) ^ ((bcol >> 1) & 3);
    size_t o = (size_t)(mcb * 256 + bcol) * H1 + bkc * 8;
    srcBh[it] = Bhi + o;
    srcBl[it] = Blo + o;
    dstBh[it] = Bs_hi + ch * 8;
    dstBl[it] = Bs_lo + ch * 8;
  }

  // fragment read offset (halfs): row li, k-chunk slot (g ^ swz(li))
  const int fo = li * 32 + ((g ^ ((li >> 1) & 3)) * 8);
  const _Float16* aph = As_hi + fo;
  const _Float16* apl = As_lo + fo;
  const _Float16* bph = Bs_hi + w * 1024 + fo;
  const _Float16* bpl = Bs_lo + w * 1024 + fo;

  f32x4 acc[4][2];
#pragma unroll
  for (int m = 0; m < 4; m++)
#pragma unroll
    for (int n = 0; n < 2; n++) acc[m][n] = (f32x4){0.f, 0.f, 0.f, 0.f};

  for (int ks = 0; ks < H1 / 32; ++ks) {
    __syncthreads();                 // previous step's ds_reads done
    GLD16(srcA, dstA);
    GLD16(srcBh[0], dstBh[0]);
    GLD16(srcBh[1], dstBh[1]);
    GLD16(srcBl[0], dstBl[0]);
    GLD16(srcBl[1], dstBl[1]);
    srcA += 32;
    srcBh[0] += 32; srcBh[1] += 32;
    srcBl[0] += 32; srcBl[1] += 32;
    __syncthreads();                 // compiler drains vmcnt(0) here
    h8 bh0 = *(const h8*)(bph);
    h8 bh1 = *(const h8*)(bph + 512);
    h8 bl0 = *(const h8*)(bpl);
    h8 bl1 = *(const h8*)(bpl + 512);
#pragma unroll
    for (int m = 0; m < 4; m++) {
      h8 ah = *(const h8*)(aph + m * 512);
      h8 al = *(const h8*)(apl + m * 512);
      acc[m][0] = __builtin_amdgcn_mfma_f32_16x16x32_f16(ah, bh0, acc[m][0], 0, 0, 0);
      acc[m][0] = __builtin_amdgcn_mfma_f32_16x16x32_f16(ah, bl0, acc[m][0], 0, 0, 0);
      acc[m][0] = __builtin_amdgcn_mfma_f32_16x16x32_f16(al, bh0, acc[m][0], 0, 0, 0);
      acc[m][1] = __builtin_amdgcn_mfma_f32_16x16x32_f16(ah, bh1, acc[m][1], 0, 0, 0);
      acc[m][1] = __builtin_amdgcn_mfma_f32_16x16x32_f16(ah, bl1, acc[m][1], 0, 0, 0);
      acc[m][1] = __builtin_amdgcn_mfma_f32_16x16x32_f16(al, bh1, acc[m][1], 0, 0, 0);
    }
  }

  // ---- fused epilogue ----
  const float interp = 1.0f / (1.0f + expf(-interp_p[0]));
  const float w_a = 1.0f - interp;
  const float spike = interp * 100.0f;
  const float inv = 1.0f / 65536.0f;             // undo the 256*256 scaling
#pragma unroll
  for (int m = 0; m < 4; m++) {
#pragma unroll
    for (int r = 0; r < 4; r++) {
      const int rl = m * 16 + g * 4 + r;         // C/D: row=(lane>>4)*4+reg
      const size_t nrow = rowBase + rl;
      const int kb = kmin[nrow * M_CB + mcb];
      const float* grow = gumbel + (nrow * M_CB + mcb) * K_CB;
      float bv = -INFINITY;
      int bi = 0;
#pragma unroll
      for (int n = 0; n < 2; n++) {
        const int c = w * 32 + n * 16 + li;      // C/D: col=lane&15
        float a = acc[m][n][r] * inv + bias[mcb * K_CB + c];
        a = fmaxf(a, 0.0f);
        float l = w_a * a;
        if (c == kb) l += spike;
        l += grow[c];
        if (l > bv) { bv = l; bi = c; }          // ascending c: strict >
      }
#pragma unroll
      for (int o = 1; o < 16; o <<= 1) {         // reduce over the 16 cols
        float ov = __shfl_xor(bv, o);
        int oi = __shfl_xor(bi, o);
        if (ov > bv || (ov == bv && oi < bi)) { bv = ov; bi = oi; }
      }
      if (li == 0) { redV[rl][w] = bv; redI[rl][w] = bi; }
    }
  }
  __syncthreads();
  if (tid < 64) {
    float bv = redV[tid][0];
    int bi = redI[tid][0];
#pragma unroll
    for (int t2 = 1; t2 < 8; t2++) {
      float v = redV[tid][t2];
      int i2 = redI[tid][t2];
      if (v > bv || (v == bv && i2 < bi)) { bv = v; bi = i2; }
    }
    bestk[tid] = bi;
  }
  __syncthreads();
#pragma unroll
  for (int j = 0; j < 8; j++) {
    int pos = j * 512 + tid;       // 4096 float4 slots of the 64x256 tile
    int r = pos >> 6;
    int c = (pos & 63) * 4;
    int kb2 = bestk[r];
    float4 v;
    v.x = (c + 0 == kb2) ? 1.0f : 0.0f;
    v.y = (c + 1 == kb2) ? 1.0f : 0.0f;
    v.z = (c + 2 == kb2) ? 1.0f : 0.0f;
    v.w = (c + 3 == kb2) ? 1.0f : 0.0f;
    *(float4*)(out + ((size_t)(rowBase + r) * M_CB + mcb) * K_CB + c) = v;
  }
}

// ---------------------------------------------------------------------------
// Kernel 5b (fallback path): original fp32 fused GEMM2 (verified baseline).
// ---------------------------------------------------------------------------
__global__ __launch_bounds__(512) void k_gemm2_fused_f32(
    const float* __restrict__ A, const float* __restrict__ B,
    const float* __restrict__ bias, const int* __restrict__ kmin,
    const float* __restrict__ interp_p, const float* __restrict__ gumbel,
    float* __restrict__ out) {
  __shared__ float As[16][132];
  __shared__ float Bs[16][260];
  __shared__ float redV[128][32];
  __shared__ int redI[128][32];
  __shared__ int bestk[128];
  int tid = threadIdx.x;
  int rowBase = blockIdx.x * 128;
  int m = blockIdx.y;
  int tx = tid & 31, ty = tid >> 5;
  int ar = tid >> 2;
  int ac = (tid & 3) * 4;
  int br = tid >> 6;
  int bc = (tid & 63) * 4;
  float acc[8][8] = {};
  const float* Aptr = A + (size_t)(rowBase + ar) * H1 + ac;
  const float* Bptr0 = B + (size_t)br * H2 + m * K_CB + bc;
  const float* Bptr1 = B + (size_t)(br + 8) * H2 + m * K_CB + bc;
  for (int k0 = 0; k0 < H1; k0 += 16) {
    float4 a0 = *(const float4*)(Aptr + k0);
    float4 b0 = *(const float4*)(Bptr0 + (size_t)k0 * H2);
    float4 b1 = *(const float4*)(Bptr1 + (size_t)k0 * H2);
    __syncthreads();
    As[ac + 0][ar] = a0.x; As[ac + 1][ar] = a0.y;
    As[ac + 2][ar] = a0.z; As[ac + 3][ar] = a0.w;
    *(float4*)&Bs[br][bc] = b0;
    *(float4*)&Bs[br + 8][bc] = b1;
    __syncthreads();
#pragma unroll
    for (int kk = 0; kk < 16; kk++) {
      float av[8], bv[8];
      *(float4*)&av[0] = *(const float4*)&As[kk][ty * 8];
      *(float4*)&av[4] = *(const float4*)&As[kk][ty * 8 + 4];
      *(float4*)&bv[0] = *(const float4*)&Bs[kk][tx * 8];
      *(float4*)&bv[4] = *(const float4*)&Bs[kk][tx * 8 + 4];
#pragma unroll
      for (int i = 0; i < 8; i++)
#pragma unroll
        for (int j = 0; j < 8; j++)
          acc[i][j] = fmaf(av[i], bv[j], acc[i][j]);
    }
  }
  float interp = 1.0f / (1.0f + expf(-interp_p[0]));
  float w_a = 1.0f - interp;
  float spike = interp * 100.0f;
#pragma unroll
  for (int i = 0; i < 8; i++) {
    int r = ty * 8 + i;
    int n = rowBase + r;
    int kb = kmin[(size_t)n * M_CB + m];
    const float* grow = gumbel + ((size_t)n * M_CB + m) * K_CB;
    float bv = -INFINITY;
    int bi = 0;
#pragma unroll
    for (int j = 0; j < 8; j++) {
      int c = tx * 8 + j;
      float a = fmaxf(acc[i][j] + bias[m * K_CB + c], 0.0f);
      float l = w_a * a;
      if (c == kb) l += spike;
      l += grow[c];
      if (l > bv) { bv = l; bi = c; }
    }
    redV[r][tx] = bv;
    redI[r][tx] = bi;
  }
  __syncthreads();
  if (tid < 128) {
    float bv = redV[tid][0];
    int bi = redI[tid][0];
    for (int t2 = 1; t2 < 32; t2++) {
      float v = redV[tid][t2];
      int i2 = redI[tid][t2];
      if (v > bv || (v == bv && i2 < bi)) { bv = v; bi = i2; }
    }
    bestk[tid] = bi;
  }
  __syncthreads();
#pragma unroll
  for (int j = 0; j < 16; j++) {
    int pos = j * 512 + tid;
    int r = pos >> 6;
    int c = (pos & 63) * 4;
    int kb = bestk[r];
    float4 v;
    v.x = (c + 0 == kb) ? 1.0f : 0.0f;
    v.y = (c + 1 == kb) ? 1.0f : 0.0f;
    v.z = (c + 2 == kb) ? 1.0f : 0.0f;
    v.w = (c + 3 == kb) ? 1.0f : 0.0f;
    *(float4*)(out + ((size_t)(rowBase + r) * M_CB + m) * K_CB + c) = v;
  }
}

// ---------------------------------------------------------------------------
extern "C" void kernel_launch(void* const* d_in, const int* in_sizes, int n_in,
                              void* d_out, int out_size, void* d_ws,
                              size_t ws_size, hipStream_t stream) {
  (void)in_sizes; (void)n_in; (void)out_size;
  const float* x   = (const float*)d_in[0];
  const float* cb  = (const float*)d_in[1];
  const float* g   = (const float*)d_in[2];
  const float* be  = (const float*)d_in[3];
  const float* W1  = (const float*)d_in[4];
  const float* b1  = (const float*)d_in[5];
  const float* W2  = (const float*)d_in[6];
  const float* b2  = (const float*)d_in[7];
  const float* ip  = (const float*)d_in[8];
  const float* gum = (const float*)d_in[9];
  float* out = (float*)d_out;
  char* ws = (char*)d_ws;

  if (ws_size >= (size_t)832569344) {
    // ---- new split-fp16 MFMA path ----
    float* xn     = (float*)(ws);                       //  25,165,824 B
    int* kmn      = (int*)(ws + 25165824);              //   2,097,152 B
    _Float16* hhi = (_Float16*)(ws + 27262976);         // 134,217,728 B
    _Float16* hlo = (_Float16*)(ws + 161480704);        // 134,217,728 B
    _Float16* whi = (_Float16*)(ws + 295698432);        // 268,435,456 B
    _Float16* wlo = (_Float16*)(ws + 564133888);        // 268,435,456 B

    k_w2split<<<dim3(128, 256), 256, 0, stream>>>(W2, whi, wlo);
    k_layernorm<<<N_ROWS, 256, 0, stream>>>(x, g, be, xn);
    k_pq_argmin<<<dim3(N_ROWS, 16), 256, 0, stream>>>(x, cb, kmn);
    k_gemm1_tanh_split<<<dim3(64, 64), 256, 0, stream>>>(xn, W1, b1, hhi, hlo);
    k_gemm2_mfma<<<dim3(128, 64), 512, 0, stream>>>(hhi, hlo, whi, wlo, b2,
                                                    kmn, ip, gum, out);
  } else {
    // ---- fallback: previous verified fp32 path (needs only ~296 MB) ----
    float* xn = (float*)(ws);
    float* h  = (float*)(ws + 25165824);
    int* kmn  = (int*)(ws + 25165824 + 268435456);
    k_layernorm<<<N_ROWS, 256, 0, stream>>>(x, g, be, xn);
    k_pq_argmin<<<dim3(N_ROWS, 16), 256, 0, stream>>>(x, cb, kmn);
    k_gemm1_tanh_f32<<<dim3(64, 64), 256, 0, stream>>>(xn, W1, b1, h);
    k_gemm2_fused_f32<<<dim3(64, 64), 512, 0, stream>>>(h, W2, b2, kmn, ip,
                                                        gum, out);
  }
}